// Round 3
// baseline (185.802 us; speedup 1.0000x reference)
//
#include <hip/hip_runtime.h>

typedef unsigned short u16;
typedef __bf16 bf16x8 __attribute__((ext_vector_type(8)));
typedef float f32x4 __attribute__((ext_vector_type(4)));

#define D_MODEL 1024
#define NH 16
#define DKD 64
#define BB 2
#define SS 2048
// log2(e)/8: folded into Q at projection time
#define QSCL 0.18033688011112042f

__device__ __forceinline__ u16 f2bf(float f) {
  union { float f; unsigned u; } x; x.f = f;
  unsigned r = x.u + 0x7fffu + ((x.u >> 16) & 1u);
  return (u16)(r >> 16);
}

__device__ __forceinline__ void gld16(const u16* g, u16* l) {
  __builtin_amdgcn_global_load_lds((__attribute__((address_space(1))) void*)(g),
                                   (__attribute__((address_space(3))) void*)(l),
                                   16, 0, 0);
}

// ---------------- prep: fp32 -> bf16 activation convert ----------------
extern "C" __global__ void __launch_bounds__(256) kprep_conv(
    const float* __restrict__ q, const float* __restrict__ k, const float* __restrict__ v,
    u16* __restrict__ xq, u16* __restrict__ xk, u16* __restrict__ xv)
{
  int z = blockIdx.y;
  const float* s = z == 0 ? q : (z == 1 ? k : v);
  u16* d = z == 0 ? xq : (z == 1 ? xk : xv);
  int i = (blockIdx.x * 256 + threadIdx.x) * 4;
  float4 val = *(const float4*)(s + i);
  ushort4 o;
  o.x = f2bf(val.x); o.y = f2bf(val.y); o.z = f2bf(val.z); o.w = f2bf(val.w);
  *(ushort4*)(d + i) = o;
}

// ---------------- prep: weight transpose + bf16 convert ----------------
extern "C" __global__ void __launch_bounds__(256) kprep_wt(
    const float* __restrict__ w0, const float* __restrict__ w1,
    const float* __restrict__ w2, const float* __restrict__ w3,
    u16* __restrict__ o0, u16* __restrict__ o1, u16* __restrict__ o2, u16* __restrict__ o3)
{
  const float* src; u16* dst;
  switch (blockIdx.z) {
    case 0: src = w0; dst = o0; break;
    case 1: src = w1; dst = o1; break;
    case 2: src = w2; dst = o2; break;
    default: src = w3; dst = o3; break;
  }
  __shared__ float t[32][33];
  int n0 = blockIdx.x * 32, k0 = blockIdx.y * 32;
  int tx = threadIdx.x & 31, ty = threadIdx.x >> 5;
  #pragma unroll
  for (int i = 0; i < 32; i += 8)
    t[ty + i][tx] = src[(k0 + ty + i) * D_MODEL + n0 + tx];
  __syncthreads();
  #pragma unroll
  for (int i = 0; i < 32; i += 8)
    dst[(size_t)(n0 + ty + i) * D_MODEL + k0 + tx] = f2bf(t[tx][ty + i]);
}

// ---------------- prep: log2(weights + 1e-20) - 16 (fixed-max softmax bias) ----------------
extern "C" __global__ void __launch_bounds__(256) klw(
    const float* __restrict__ w, float* __restrict__ lw)
{
  int i = blockIdx.x * 256 + threadIdx.x;
  if (i < BB * SS) lw[i] = log2f(w[i] + 1e-20f) - 16.0f;
}

// ---------------- shared GEMM core: C(128x128) = A(128xK) * Bt(128xK)^T ----------------
__device__ __forceinline__ void gemm_tile(const u16* __restrict__ Ag, const u16* __restrict__ Bg,
                                          u16* As, u16* Bs, f32x4 acc[4][4], int tid)
{
  int lane = tid & 63;
  int lr = lane & 15, lg = lane >> 4;
  int w = tid >> 6, wr = w >> 1, wc = w & 1;
  for (int k0 = 0; k0 < D_MODEL; k0 += 32) {
    #pragma unroll
    for (int c = 0; c < 2; ++c) {
      int idx = tid + c * 256;
      int row = idx >> 2, col = (idx & 3) * 8;
      gld16(Ag + row * D_MODEL + k0 + col, As + idx * 8);
      gld16(Bg + row * D_MODEL + k0 + col, Bs + idx * 8);
    }
    __syncthreads();
    bf16x8 af[4], bfr[4];
    #pragma unroll
    for (int mi = 0; mi < 4; ++mi)
      af[mi] = *(const bf16x8*)(As + (wr * 64 + mi * 16 + lr) * 32 + lg * 8);
    #pragma unroll
    for (int nj = 0; nj < 4; ++nj)
      bfr[nj] = *(const bf16x8*)(Bs + (wc * 64 + nj * 16 + lr) * 32 + lg * 8);
    #pragma unroll
    for (int mi = 0; mi < 4; ++mi)
      #pragma unroll
      for (int nj = 0; nj < 4; ++nj)
        acc[mi][nj] = __builtin_amdgcn_mfma_f32_16x16x32_bf16(af[mi], bfr[nj], acc[mi][nj], 0, 0, 0);
    __syncthreads();
  }
}

// ---------------- fused QKV projection ----------------
// z==0: Q scaled by QSCL, layout (b,h,s,dk). z==1: K, layout (b,h,s,dk).
// z==2: V TRANSPOSED, layout (b,h,dk,s).
extern "C" __global__ void __launch_bounds__(256) kgemm_qkv(
    const u16* __restrict__ xq, const u16* __restrict__ xk, const u16* __restrict__ xv,
    const u16* __restrict__ wqt, const u16* __restrict__ wkt, const u16* __restrict__ wvt,
    const float* __restrict__ bq, const float* __restrict__ bk, const float* __restrict__ bv,
    u16* __restrict__ Qb, u16* __restrict__ Kb, u16* __restrict__ Vb)
{
  __shared__ u16 As[128 * 32], Bs[128 * 32];
  int z = blockIdx.z;
  const u16* X  = z == 0 ? xq : (z == 1 ? xk : xv);
  const u16* Wt = z == 0 ? wqt : (z == 1 ? wkt : wvt);
  const float* bias = z == 0 ? bq : (z == 1 ? bk : bv);
  u16* dst = z == 0 ? Qb : (z == 1 ? Kb : Vb);
  int tid = threadIdx.x;
  f32x4 zero = {0.f, 0.f, 0.f, 0.f};
  f32x4 acc[4][4];
  #pragma unroll
  for (int i = 0; i < 4; ++i)
    #pragma unroll
    for (int j = 0; j < 4; ++j) acc[i][j] = zero;
  int m0 = blockIdx.y * 128, n0 = blockIdx.x * 128;
  gemm_tile(X + (size_t)m0 * D_MODEL, Wt + (size_t)n0 * D_MODEL, As, Bs, acc, tid);
  int lane = tid & 63, lr = lane & 15, lg = lane >> 4;
  int w = tid >> 6, wr = w >> 1, wc = w & 1;
  if (z == 2) {
    // V^T epilogue: (b,h,dk,s); the f32x4's j index is contiguous in s -> 8B stores
    #pragma unroll
    for (int mi = 0; mi < 4; ++mi)
      #pragma unroll
      for (int nj = 0; nj < 4; ++nj) {
        int n = n0 + wc * 64 + nj * 16 + lr;
        float bs = bias[n];
        int h = n >> 6, dk = n & 63;
        int m = m0 + wr * 64 + mi * 16 + lg * 4;
        int b = m >> 11, s = m & 2047;
        ushort4 o;
        o.x = f2bf(acc[mi][nj][0] + bs);
        o.y = f2bf(acc[mi][nj][1] + bs);
        o.z = f2bf(acc[mi][nj][2] + bs);
        o.w = f2bf(acc[mi][nj][3] + bs);
        *(ushort4*)&dst[(((size_t)(b * NH + h)) * DKD + dk) * SS + s] = o;
      }
  } else {
    float scl = (z == 0) ? QSCL : 1.0f;
    #pragma unroll
    for (int mi = 0; mi < 4; ++mi)
      #pragma unroll
      for (int nj = 0; nj < 4; ++nj) {
        int n = n0 + wc * 64 + nj * 16 + lr;
        float bs = bias[n];
        int h = n >> 6, dk = n & 63;
        #pragma unroll
        for (int j = 0; j < 4; ++j) {
          int m = m0 + wr * 64 + mi * 16 + lg * 4 + j;
          int b = m >> 11, s = m & 2047;
          dst[(((size_t)(b * NH + h)) * SS + s) * DKD + dk] = f2bf((acc[mi][nj][j] + bs) * scl);
        }
      }
  }
}

// ---------------- output projection ----------------
extern "C" __global__ void __launch_bounds__(256) kgemm_o(
    const u16* __restrict__ AO, const u16* __restrict__ wot,
    const float* __restrict__ bo, float* __restrict__ out)
{
  __shared__ u16 As[128 * 32], Bs[128 * 32];
  int tid = threadIdx.x;
  f32x4 zero = {0.f, 0.f, 0.f, 0.f};
  f32x4 acc[4][4];
  #pragma unroll
  for (int i = 0; i < 4; ++i)
    #pragma unroll
    for (int j = 0; j < 4; ++j) acc[i][j] = zero;
  int m0 = blockIdx.y * 128, n0 = blockIdx.x * 128;
  gemm_tile(AO + (size_t)m0 * D_MODEL, wot + (size_t)n0 * D_MODEL, As, Bs, acc, tid);
  int lane = tid & 63, lr = lane & 15, lg = lane >> 4;
  int w = tid >> 6, wr = w >> 1, wc = w & 1;
  #pragma unroll
  for (int mi = 0; mi < 4; ++mi)
    #pragma unroll
    for (int nj = 0; nj < 4; ++nj) {
      int n = n0 + wc * 64 + nj * 16 + lr;
      float bs = bo[n];
      #pragma unroll
      for (int j = 0; j < 4; ++j) {
        int m = m0 + wr * 64 + mi * 16 + lg * 4 + j;
        out[(size_t)m * D_MODEL + n] = acc[mi][nj][j] + bs;
      }
    }
}

// ---------------- flash attention, fixed-max softmax, gld16+swizzle staging ----------------
// Qb: (b,h,s,dk) bf16, PRE-SCALED by log2(e)/8. Kb: (b,h,s,dk) bf16. Vb: (b,h,dk,s) bf16.
// lw2: (b,s) f32 = log2(w+1e-20)-16. AO: (b,s,1024) bf16.
// Per block: 64 q rows, 4 waves x 16. St = K*Q^T (kv rows, q cols); p = exp2(st + lw2);
// O^T = V^T * P^T (O cols = q = lane&15). No online max: scores statically bounded << 16.
extern "C" __global__ void __launch_bounds__(256) kattn(
    const u16* __restrict__ Qb, const u16* __restrict__ Kb, const u16* __restrict__ Vb,
    const float* __restrict__ lw2, u16* __restrict__ AO)
{
  // linear [64][64] u16 tiles (128B rows); chunk-XOR swizzle on global source + reads
  __shared__ __align__(16) u16 Ks[64 * 64];
  __shared__ __align__(16) u16 Vs[64 * 64];
  __shared__ __align__(16) unsigned Pt[4][16 * 36];  // per-wave: [q=16][kv-pair words, stride 36]

  int tid = threadIdx.x, lane = tid & 63, w = tid >> 6;
  int lr = lane & 15, lg = lane >> 4;
  int bh = blockIdx.y, b = bh >> 4, h = bh & 15;
  int q0 = blockIdx.x * 64;

  const u16* Qg = Qb + ((size_t)bh * SS + q0 + w * 16) * DKD;
  const u16* Kg = Kb + (size_t)bh * SS * DKD;
  const u16* Vg = Vb + (size_t)bh * DKD * SS;   // rows = dk, cols = s
  const float* lwb = lw2 + b * SS;

  // Q as B-fragment: col = q = lr, k-elems = lg*8..+7 per 32-chunk ki
  bf16x8 qf[2];
  qf[0] = *(const bf16x8*)(Qg + lr * DKD + lg * 8);
  qf[1] = *(const bf16x8*)(Qg + lr * DKD + 32 + lg * 8);

  f32x4 zero = {0.f, 0.f, 0.f, 0.f};
  f32x4 acco[4] = {zero, zero, zero, zero};   // O^T[dk = dn*16+lg*4+j][q = lr]
  float lsum = 0.f;

  // staging geometry: idx = c*256+tid; row = idx>>3 (64 rows), c3 = idx&7 (16B chunk)
  // LDS[row][c3] = Global[row][c3 ^ (row&7)]  (linear LDS dest for gld16; swizzle on src)
  int sidx0 = tid, sidx1 = tid + 256;
  int srow0 = sidx0 >> 3, sc0 = ((sidx0 & 7) ^ (srow0 & 7)) * 8;
  int srow1 = sidx1 >> 3, sc1 = ((sidx1 & 7) ^ (srow1 & 7)) * 8;

  for (int kv0 = 0; kv0 < SS; kv0 += 64) {
    gld16(Kg + (size_t)(kv0 + srow0) * DKD + sc0, Ks + sidx0 * 8);
    gld16(Kg + (size_t)(kv0 + srow1) * DKD + sc1, Ks + sidx1 * 8);
    gld16(Vg + (size_t)srow0 * SS + kv0 + sc0, Vs + sidx0 * 8);
    gld16(Vg + (size_t)srow1 * SS + kv0 + sc1, Vs + sidx1 * 8);
    __syncthreads();   // drains vmcnt: tile visible

    // ---- St = K * Q^T : St[kv = nk*16 + lg*4 + j][q = lr] ----
    f32x4 st[4] = {zero, zero, zero, zero};
    #pragma unroll
    for (int ki = 0; ki < 2; ++ki) {
      bf16x8 kf[4];
      #pragma unroll
      for (int nk = 0; nk < 4; ++nk)
        kf[nk] = *(const bf16x8*)&Ks[(nk * 16 + lr) * 64 + (((ki * 4 + lg) ^ (lr & 7)) * 8)];
      #pragma unroll
      for (int nk = 0; nk < 4; ++nk)
        st[nk] = __builtin_amdgcn_mfma_f32_16x16x32_bf16(kf[nk], qf[ki], st[nk], 0, 0, 0);
    }

    // ---- p = exp2(st + lw2) ; accumulate per-lane lsum; pack to Pt ----
    #pragma unroll
    for (int nk = 0; nk < 4; ++nk) {
      float4 lwv = *(const float4*)(lwb + kv0 + nk * 16 + lg * 4);
      float p0 = exp2f(st[nk][0] + lwv.x);
      float p1 = exp2f(st[nk][1] + lwv.y);
      float p2 = exp2f(st[nk][2] + lwv.z);
      float p3 = exp2f(st[nk][3] + lwv.w);
      lsum += (p0 + p1) + (p2 + p3);
      union { unsigned u; __bf16 b2[2]; } c0, c1;
      c0.b2[0] = (__bf16)p0; c0.b2[1] = (__bf16)p1;
      c1.b2[0] = (__bf16)p2; c1.b2[1] = (__bf16)p3;
      *(uint2*)&Pt[w][lr * 36 + nk * 8 + lg * 2] = make_uint2(c0.u, c1.u);
    }

    // ---- O^T += V^T * P^T (Pt wave-private; same-wave DS ordering) ----
    #pragma unroll
    for (int ks = 0; ks < 2; ++ks) {
      bf16x8 F = *(const bf16x8*)&Pt[w][lr * 36 + ks * 16 + lg * 4];
      #pragma unroll
      for (int dn = 0; dn < 4; ++dn) {
        bf16x8 vf = *(const bf16x8*)&Vs[(dn * 16 + lr) * 64 + (((ks * 4 + lg) ^ (lr & 7)) * 8)];
        acco[dn] = __builtin_amdgcn_mfma_f32_16x16x32_bf16(vf, F, acco[dn], 0, 0, 0);
      }
    }
    __syncthreads();   // all waves done reading before next stage overwrites
  }

  // ---- epilogue: reduce lsum across kv-slices (lg groups), normalize, store ----
  lsum += __shfl_xor(lsum, 16);
  lsum += __shfl_xor(lsum, 32);
  float inv = 1.0f / lsum;
  int s = q0 + w * 16 + lr;
  size_t base = ((size_t)b * SS + s) * D_MODEL + h * DKD;
  #pragma unroll
  for (int dn = 0; dn < 4; ++dn) {
    ushort4 o;
    o.x = f2bf(acco[dn][0] * inv);
    o.y = f2bf(acco[dn][1] * inv);
    o.z = f2bf(acco[dn][2] * inv);
    o.w = f2bf(acco[dn][3] * inv);
    *(ushort4*)(AO + base + dn * 16 + lg * 4) = o;
  }
}

extern "C" void kernel_launch(void* const* d_in, const int* in_sizes, int n_in,
                              void* d_out, int out_size, void* d_ws, size_t ws_size,
                              hipStream_t stream) {
  const float* query = (const float*)d_in[0];
  const float* key_  = (const float*)d_in[1];
  const float* value = (const float*)d_in[2];
  const float* wts   = (const float*)d_in[3];
  const float* wq = (const float*)d_in[4];
  const float* bq = (const float*)d_in[5];
  const float* wk = (const float*)d_in[6];
  const float* bk = (const float*)d_in[7];
  const float* wv = (const float*)d_in[8];
  const float* bv = (const float*)d_in[9];
  const float* wo = (const float*)d_in[10];
  const float* bo = (const float*)d_in[11];
  float* out = (float*)d_out;

  char* ws = (char*)d_ws;
  const size_t MB = 1024 * 1024;
  u16* Xq  = (u16*)(ws + 0 * MB);
  u16* Xk  = (u16*)(ws + 8 * MB);
  u16* Xv  = (u16*)(ws + 16 * MB);
  u16* WqT = (u16*)(ws + 24 * MB);
  u16* WkT = (u16*)(ws + 26 * MB);
  u16* WvT = (u16*)(ws + 28 * MB);
  u16* WoT = (u16*)(ws + 30 * MB);
  u16* Qb  = (u16*)(ws + 32 * MB);
  u16* Kb  = (u16*)(ws + 40 * MB);
  u16* Vb  = (u16*)(ws + 48 * MB);
  u16* AO  = (u16*)(ws + 56 * MB);
  float* lwbuf = (float*)(ws + 64 * MB);

  kprep_conv<<<dim3(4096, 3), 256, 0, stream>>>(query, key_, value, Xq, Xk, Xv);
  kprep_wt<<<dim3(32, 32, 4), 256, 0, stream>>>(wq, wk, wv, wo, WqT, WkT, WvT, WoT);
  klw<<<16, 256, 0, stream>>>(wts, lwbuf);
  kgemm_qkv<<<dim3(8, 32, 3), 256, 0, stream>>>(Xq, Xk, Xv, WqT, WkT, WvT, bq, bk, bv, Qb, Kb, Vb);
  kattn<<<dim3(32, 32), 256, 0, stream>>>(Qb, Kb, Vb, lwbuf, AO);
  kgemm_o<<<dim3(8, 32), 256, 0, stream>>>(AO, WoT, bo, out);
}

// Round 4
// 159.901 us; speedup vs baseline: 1.1620x; 1.1620x over previous
//
#include <hip/hip_runtime.h>

typedef unsigned short u16;
typedef __bf16 bf16x8 __attribute__((ext_vector_type(8)));
typedef float f32x4 __attribute__((ext_vector_type(4)));

#define D_MODEL 1024
#define NH 16
#define DKD 64
#define BB 2
#define SS 2048
// log2(e)/8: folded into Q at projection time
#define QSCL 0.18033688011112042f

__device__ __forceinline__ u16 f2bf(float f) {
  union { float f; unsigned u; } x; x.f = f;
  unsigned r = x.u + 0x7fffu + ((x.u >> 16) & 1u);
  return (u16)(r >> 16);
}

__device__ __forceinline__ void gld16(const u16* g, u16* l) {
  __builtin_amdgcn_global_load_lds((__attribute__((address_space(1))) void*)(g),
                                   (__attribute__((address_space(3))) void*)(l),
                                   16, 0, 0);
}

// ---------------- prep: fp32 -> bf16 activation convert ----------------
extern "C" __global__ void __launch_bounds__(256) kprep_conv(
    const float* __restrict__ q, const float* __restrict__ k, const float* __restrict__ v,
    u16* __restrict__ xq, u16* __restrict__ xk, u16* __restrict__ xv)
{
  int z = blockIdx.y;
  const float* s = z == 0 ? q : (z == 1 ? k : v);
  u16* d = z == 0 ? xq : (z == 1 ? xk : xv);
  int i = (blockIdx.x * 256 + threadIdx.x) * 4;
  float4 val = *(const float4*)(s + i);
  ushort4 o;
  o.x = f2bf(val.x); o.y = f2bf(val.y); o.z = f2bf(val.z); o.w = f2bf(val.w);
  *(ushort4*)(d + i) = o;
}

// ---------------- prep: weight transpose + bf16 convert ----------------
extern "C" __global__ void __launch_bounds__(256) kprep_wt(
    const float* __restrict__ w0, const float* __restrict__ w1,
    const float* __restrict__ w2, const float* __restrict__ w3,
    u16* __restrict__ o0, u16* __restrict__ o1, u16* __restrict__ o2, u16* __restrict__ o3)
{
  const float* src; u16* dst;
  switch (blockIdx.z) {
    case 0: src = w0; dst = o0; break;
    case 1: src = w1; dst = o1; break;
    case 2: src = w2; dst = o2; break;
    default: src = w3; dst = o3; break;
  }
  __shared__ float t[32][33];
  int n0 = blockIdx.x * 32, k0 = blockIdx.y * 32;
  int tx = threadIdx.x & 31, ty = threadIdx.x >> 5;
  #pragma unroll
  for (int i = 0; i < 32; i += 8)
    t[ty + i][tx] = src[(k0 + ty + i) * D_MODEL + n0 + tx];
  __syncthreads();
  #pragma unroll
  for (int i = 0; i < 32; i += 8)
    dst[(size_t)(n0 + ty + i) * D_MODEL + k0 + tx] = f2bf(t[tx][ty + i]);
}

// ---------------- prep: log2(weights + 1e-20) - 16 (fixed-max softmax bias) ----------------
extern "C" __global__ void __launch_bounds__(256) klw(
    const float* __restrict__ w, float* __restrict__ lw)
{
  int i = blockIdx.x * 256 + threadIdx.x;
  if (i < BB * SS) lw[i] = log2f(w[i] + 1e-20f) - 16.0f;
}

// ---------------- V transpose: (b,h,s,dk) -> (b,h,dk,s) ----------------
extern "C" __global__ void __launch_bounds__(256) ktrans_v(
    const u16* __restrict__ src, u16* __restrict__ dst)
{
  __shared__ u16 T[64][72];
  int bh = blockIdx.y; int s0 = blockIdx.x * 64;
  int tid = threadIdx.x;
  int r = tid >> 3, c = (tid & 7) * 8;
  #pragma unroll
  for (int i = 0; i < 2; ++i)
    *(bf16x8*)&T[r + i * 32][c] = *(const bf16x8*)&src[((size_t)bh * SS + s0 + r + i * 32) * DKD + c];
  __syncthreads();
  #pragma unroll
  for (int i = 0; i < 2; ++i) {
    int dk = r + i * 32;
    ushort4 o0, o1;
    o0.x = T[c + 0][dk]; o0.y = T[c + 1][dk]; o0.z = T[c + 2][dk]; o0.w = T[c + 3][dk];
    o1.x = T[c + 4][dk]; o1.y = T[c + 5][dk]; o1.z = T[c + 6][dk]; o1.w = T[c + 7][dk];
    *(ushort4*)&dst[((size_t)bh * DKD + dk) * SS + s0 + c] = o0;
    *(ushort4*)&dst[((size_t)bh * DKD + dk) * SS + s0 + c + 4] = o1;
  }
}

// ---------------- shared GEMM core: C(128x128) = A(128xK) * Bt(128xK)^T ----------------
__device__ __forceinline__ void gemm_tile(const u16* __restrict__ Ag, const u16* __restrict__ Bg,
                                          u16* As, u16* Bs, f32x4 acc[4][4], int tid)
{
  int lane = tid & 63;
  int lr = lane & 15, lg = lane >> 4;
  int w = tid >> 6, wr = w >> 1, wc = w & 1;
  for (int k0 = 0; k0 < D_MODEL; k0 += 32) {
    #pragma unroll
    for (int c = 0; c < 2; ++c) {
      int idx = tid + c * 256;
      int row = idx >> 2, col = (idx & 3) * 8;
      gld16(Ag + row * D_MODEL + k0 + col, As + idx * 8);
      gld16(Bg + row * D_MODEL + k0 + col, Bs + idx * 8);
    }
    __syncthreads();
    bf16x8 af[4], bfr[4];
    #pragma unroll
    for (int mi = 0; mi < 4; ++mi)
      af[mi] = *(const bf16x8*)(As + (wr * 64 + mi * 16 + lr) * 32 + lg * 8);
    #pragma unroll
    for (int nj = 0; nj < 4; ++nj)
      bfr[nj] = *(const bf16x8*)(Bs + (wc * 64 + nj * 16 + lr) * 32 + lg * 8);
    #pragma unroll
    for (int mi = 0; mi < 4; ++mi)
      #pragma unroll
      for (int nj = 0; nj < 4; ++nj)
        acc[mi][nj] = __builtin_amdgcn_mfma_f32_16x16x32_bf16(af[mi], bfr[nj], acc[mi][nj], 0, 0, 0);
    __syncthreads();
  }
}

// ---------------- fused QKV projection ----------------
// z==0: Q scaled by QSCL. All outputs layout (b,h,s,dk).
extern "C" __global__ void __launch_bounds__(256) kgemm_qkv(
    const u16* __restrict__ xq, const u16* __restrict__ xk, const u16* __restrict__ xv,
    const u16* __restrict__ wqt, const u16* __restrict__ wkt, const u16* __restrict__ wvt,
    const float* __restrict__ bq, const float* __restrict__ bk, const float* __restrict__ bv,
    u16* __restrict__ Qb, u16* __restrict__ Kb, u16* __restrict__ Vb)
{
  __shared__ u16 As[128 * 32], Bs[128 * 32];
  int z = blockIdx.z;
  const u16* X  = z == 0 ? xq : (z == 1 ? xk : xv);
  const u16* Wt = z == 0 ? wqt : (z == 1 ? wkt : wvt);
  const float* bias = z == 0 ? bq : (z == 1 ? bk : bv);
  u16* dst = z == 0 ? Qb : (z == 1 ? Kb : Vb);
  int tid = threadIdx.x;
  f32x4 zero = {0.f, 0.f, 0.f, 0.f};
  f32x4 acc[4][4];
  #pragma unroll
  for (int i = 0; i < 4; ++i)
    #pragma unroll
    for (int j = 0; j < 4; ++j) acc[i][j] = zero;
  int m0 = blockIdx.y * 128, n0 = blockIdx.x * 128;
  gemm_tile(X + (size_t)m0 * D_MODEL, Wt + (size_t)n0 * D_MODEL, As, Bs, acc, tid);
  int lane = tid & 63, lr = lane & 15, lg = lane >> 4;
  int w = tid >> 6, wr = w >> 1, wc = w & 1;
  float scl = (z == 0) ? QSCL : 1.0f;
  #pragma unroll
  for (int mi = 0; mi < 4; ++mi)
    #pragma unroll
    for (int nj = 0; nj < 4; ++nj) {
      int n = n0 + wc * 64 + nj * 16 + lr;
      float bs = bias[n];
      int h = n >> 6, dk = n & 63;
      #pragma unroll
      for (int j = 0; j < 4; ++j) {
        int m = m0 + wr * 64 + mi * 16 + lg * 4 + j;
        int b = m >> 11, s = m & 2047;
        dst[(((size_t)(b * NH + h)) * SS + s) * DKD + dk] = f2bf((acc[mi][nj][j] + bs) * scl);
      }
    }
}

// ---------------- output projection ----------------
extern "C" __global__ void __launch_bounds__(256) kgemm_o(
    const u16* __restrict__ AO, const u16* __restrict__ wot,
    const float* __restrict__ bo, float* __restrict__ out)
{
  __shared__ u16 As[128 * 32], Bs[128 * 32];
  int tid = threadIdx.x;
  f32x4 zero = {0.f, 0.f, 0.f, 0.f};
  f32x4 acc[4][4];
  #pragma unroll
  for (int i = 0; i < 4; ++i)
    #pragma unroll
    for (int j = 0; j < 4; ++j) acc[i][j] = zero;
  int m0 = blockIdx.y * 128, n0 = blockIdx.x * 128;
  gemm_tile(AO + (size_t)m0 * D_MODEL, wot + (size_t)n0 * D_MODEL, As, Bs, acc, tid);
  int lane = tid & 63, lr = lane & 15, lg = lane >> 4;
  int w = tid >> 6, wr = w >> 1, wc = w & 1;
  #pragma unroll
  for (int mi = 0; mi < 4; ++mi)
    #pragma unroll
    for (int nj = 0; nj < 4; ++nj) {
      int n = n0 + wc * 64 + nj * 16 + lr;
      float bs = bo[n];
      #pragma unroll
      for (int j = 0; j < 4; ++j) {
        int m = m0 + wr * 64 + mi * 16 + lg * 4 + j;
        out[(size_t)m * D_MODEL + n] = acc[mi][nj][j] + bs;
      }
    }
}

// ---------------- flash attention: 8 waves, dbuf prefetch, fixed-max softmax ----------------
// Qb: (b,h,s,dk) bf16 PRE-SCALED by log2(e)/8. Kb: (b,h,s,dk). Vt: (b,h,dk,s).
// lw2: (b,s) f32 = log2(w+1e-20)-16. AO: (b,s,1024) bf16.
// Per block: 128 q rows, 8 waves x 16. St = K*Q^T; p = exp2(st + lw2); O^T = V^T * P^T.
extern "C" __global__ void __launch_bounds__(512) kattn(
    const u16* __restrict__ Qb, const u16* __restrict__ Kb, const u16* __restrict__ Vt,
    const float* __restrict__ lw2, u16* __restrict__ AO)
{
  __shared__ __align__(16) u16 Ks[2][64 * 64];
  __shared__ __align__(16) u16 Vs[2][64 * 64];
  __shared__ __align__(16) unsigned Pt[8][16 * 36];  // per-wave: [q=16][kv-pair words, stride 36]

  int tid = threadIdx.x, lane = tid & 63, w = tid >> 6;  // w 0..7
  int lr = lane & 15, lg = lane >> 4;
  int bh = blockIdx.y, b = bh >> 4, h = bh & 15;
  int q0 = blockIdx.x * 128;

  const u16* Qg = Qb + ((size_t)bh * SS + q0 + w * 16) * DKD;
  const u16* Kg = Kb + (size_t)bh * SS * DKD;
  const u16* Vg = Vt + (size_t)bh * DKD * SS;   // rows = dk, cols = s
  const float* lwb = lw2 + b * SS;

  // Q as B-fragment: col = q = lr, k-elems = lg*8..+7 per 32-chunk ki
  bf16x8 qf[2];
  qf[0] = *(const bf16x8*)(Qg + lr * DKD + lg * 8);
  qf[1] = *(const bf16x8*)(Qg + lr * DKD + 32 + lg * 8);

  f32x4 zero = {0.f, 0.f, 0.f, 0.f};
  f32x4 acco[4] = {zero, zero, zero, zero};   // O^T[dk = dn*16+lg*4+j][q = lr]
  float lsum = 0.f;

  // staging: 512 threads x one 16B chunk each of K and V^T tile (8KB each)
  // LDS[row][c3] = Global[row][c3 ^ (row&7)]  (linear dest for gld16; swizzle on src+read)
  int srow = tid >> 3, sc = ((tid & 7) ^ (srow & 7)) * 8;

#define STAGE(t, bi) do { \
    gld16(Kg + (size_t)((t) * 64 + srow) * DKD + sc, &Ks[bi][tid * 8]); \
    gld16(Vg + (size_t)srow * SS + (t) * 64 + sc, &Vs[bi][tid * 8]); \
  } while (0)

  STAGE(0, 0);
  for (int t = 0; t < SS / 64; ++t) {
    __syncthreads();                    // drains vmcnt: buf[t&1] ready; prev reads done
    if (t + 1 < SS / 64) STAGE(t + 1, (t + 1) & 1);
    int bi = t & 1;
    int kv0 = t * 64;

    // ---- St = K * Q^T : St[kv = nk*16 + lg*4 + j][q = lr] ----
    f32x4 st[4] = {zero, zero, zero, zero};
    __builtin_amdgcn_s_setprio(1);
    #pragma unroll
    for (int ki = 0; ki < 2; ++ki) {
      bf16x8 kf[4];
      #pragma unroll
      for (int nk = 0; nk < 4; ++nk)
        kf[nk] = *(const bf16x8*)&Ks[bi][(nk * 16 + lr) * 64 + (((ki * 4 + lg) ^ (lr & 7)) * 8)];
      #pragma unroll
      for (int nk = 0; nk < 4; ++nk)
        st[nk] = __builtin_amdgcn_mfma_f32_16x16x32_bf16(kf[nk], qf[ki], st[nk], 0, 0, 0);
    }
    __builtin_amdgcn_s_setprio(0);

    // ---- p = exp2(st + lw2); accumulate per-lane lsum; pack to Pt ----
    #pragma unroll
    for (int nk = 0; nk < 4; ++nk) {
      float4 lwv = *(const float4*)(lwb + kv0 + nk * 16 + lg * 4);
      float p0 = exp2f(st[nk][0] + lwv.x);
      float p1 = exp2f(st[nk][1] + lwv.y);
      float p2 = exp2f(st[nk][2] + lwv.z);
      float p3 = exp2f(st[nk][3] + lwv.w);
      lsum += (p0 + p1) + (p2 + p3);
      union { unsigned u; __bf16 b2[2]; } c0, c1;
      c0.b2[0] = (__bf16)p0; c0.b2[1] = (__bf16)p1;
      c1.b2[0] = (__bf16)p2; c1.b2[1] = (__bf16)p3;
      *(uint2*)&Pt[w][lr * 36 + nk * 8 + lg * 2] = make_uint2(c0.u, c1.u);
    }

    // ---- O^T += V^T * P^T (Pt wave-private; same-wave DS ordering) ----
    __builtin_amdgcn_s_setprio(1);
    #pragma unroll
    for (int ks = 0; ks < 2; ++ks) {
      bf16x8 F = *(const bf16x8*)&Pt[w][lr * 36 + ks * 16 + lg * 4];
      #pragma unroll
      for (int dn = 0; dn < 4; ++dn) {
        bf16x8 vf = *(const bf16x8*)&Vs[bi][(dn * 16 + lr) * 64 + (((ks * 4 + lg) ^ (lr & 7)) * 8)];
        acco[dn] = __builtin_amdgcn_mfma_f32_16x16x32_bf16(vf, F, acco[dn], 0, 0, 0);
      }
    }
    __builtin_amdgcn_s_setprio(0);
  }
#undef STAGE

  // ---- epilogue: reduce lsum across lg groups, normalize, store ----
  lsum += __shfl_xor(lsum, 16);
  lsum += __shfl_xor(lsum, 32);
  float inv = 1.0f / lsum;
  int s = q0 + w * 16 + lr;
  size_t base = ((size_t)b * SS + s) * D_MODEL + h * DKD;
  #pragma unroll
  for (int dn = 0; dn < 4; ++dn) {
    ushort4 o;
    o.x = f2bf(acco[dn][0] * inv);
    o.y = f2bf(acco[dn][1] * inv);
    o.z = f2bf(acco[dn][2] * inv);
    o.w = f2bf(acco[dn][3] * inv);
    *(ushort4*)(AO + base + dn * 16 + lg * 4) = o;
  }
}

extern "C" void kernel_launch(void* const* d_in, const int* in_sizes, int n_in,
                              void* d_out, int out_size, void* d_ws, size_t ws_size,
                              hipStream_t stream) {
  const float* query = (const float*)d_in[0];
  const float* key_  = (const float*)d_in[1];
  const float* value = (const float*)d_in[2];
  const float* wts   = (const float*)d_in[3];
  const float* wq = (const float*)d_in[4];
  const float* bq = (const float*)d_in[5];
  const float* wk = (const float*)d_in[6];
  const float* bk = (const float*)d_in[7];
  const float* wv = (const float*)d_in[8];
  const float* bv = (const float*)d_in[9];
  const float* wo = (const float*)d_in[10];
  const float* bo = (const float*)d_in[11];
  float* out = (float*)d_out;

  char* ws = (char*)d_ws;
  const size_t MB = 1024 * 1024;
  u16* Xq  = (u16*)(ws + 0 * MB);
  u16* Xk  = (u16*)(ws + 8 * MB);
  u16* Xv  = (u16*)(ws + 16 * MB);   // dead after kgemm_qkv; reused as VtT
  u16* WqT = (u16*)(ws + 24 * MB);
  u16* WkT = (u16*)(ws + 26 * MB);
  u16* WvT = (u16*)(ws + 28 * MB);
  u16* WoT = (u16*)(ws + 30 * MB);
  u16* Qb  = (u16*)(ws + 32 * MB);
  u16* Kb  = (u16*)(ws + 40 * MB);
  u16* Vb  = (u16*)(ws + 48 * MB);
  u16* AO  = (u16*)(ws + 56 * MB);
  float* lwbuf = (float*)(ws + 64 * MB);
  u16* VtT = (u16*)(ws + 16 * MB);   // V transposed (b,h,dk,s), overwrites Xv after use

  kprep_conv<<<dim3(4096, 3), 256, 0, stream>>>(query, key_, value, Xq, Xk, Xv);
  kprep_wt<<<dim3(32, 32, 4), 256, 0, stream>>>(wq, wk, wv, wo, WqT, WkT, WvT, WoT);
  klw<<<16, 256, 0, stream>>>(wts, lwbuf);
  kgemm_qkv<<<dim3(8, 32, 3), 256, 0, stream>>>(Xq, Xk, Xv, WqT, WkT, WvT, bq, bk, bv, Qb, Kb, Vb);
  ktrans_v<<<dim3(32, 32), 256, 0, stream>>>(Vb, VtT);
  kattn<<<dim3(16, 32), 512, 0, stream>>>(Qb, Kb, VtT, lwbuf, AO);
  kgemm_o<<<dim3(8, 32), 256, 0, stream>>>(AO, WoT, bo, out);
}

// Round 5
// 156.473 us; speedup vs baseline: 1.1874x; 1.0219x over previous
//
#include <hip/hip_runtime.h>

typedef unsigned short u16;
typedef __bf16 bf16x8 __attribute__((ext_vector_type(8)));
typedef float f32x4 __attribute__((ext_vector_type(4)));

#define D_MODEL 1024
#define NH 16
#define DKD 64
#define BB 2
#define SS 2048
// log2(e)/8: folded into Q at projection time
#define QSCL 0.18033688011112042f

__device__ __forceinline__ u16 f2bf(float f) {
  union { float f; unsigned u; } x; x.f = f;
  unsigned r = x.u + 0x7fffu + ((x.u >> 16) & 1u);
  return (u16)(r >> 16);
}

__device__ __forceinline__ void gld16(const u16* g, u16* l) {
  __builtin_amdgcn_global_load_lds((__attribute__((address_space(1))) void*)(g),
                                   (__attribute__((address_space(3))) void*)(l),
                                   16, 0, 0);
}

// ---------------- prep: fp32 -> bf16 activation convert ----------------
extern "C" __global__ void __launch_bounds__(256) kprep_conv(
    const float* __restrict__ q, const float* __restrict__ k, const float* __restrict__ v,
    u16* __restrict__ xq, u16* __restrict__ xk, u16* __restrict__ xv)
{
  int z = blockIdx.y;
  const float* s = z == 0 ? q : (z == 1 ? k : v);
  u16* d = z == 0 ? xq : (z == 1 ? xk : xv);
  int i = (blockIdx.x * 256 + threadIdx.x) * 4;
  float4 val = *(const float4*)(s + i);
  ushort4 o;
  o.x = f2bf(val.x); o.y = f2bf(val.y); o.z = f2bf(val.z); o.w = f2bf(val.w);
  *(ushort4*)(d + i) = o;
}

// ---------------- prep: weight transpose + bf16 convert ----------------
extern "C" __global__ void __launch_bounds__(256) kprep_wt(
    const float* __restrict__ w0, const float* __restrict__ w1,
    const float* __restrict__ w2, const float* __restrict__ w3,
    u16* __restrict__ o0, u16* __restrict__ o1, u16* __restrict__ o2, u16* __restrict__ o3)
{
  const float* src; u16* dst;
  switch (blockIdx.z) {
    case 0: src = w0; dst = o0; break;
    case 1: src = w1; dst = o1; break;
    case 2: src = w2; dst = o2; break;
    default: src = w3; dst = o3; break;
  }
  __shared__ float t[32][33];
  int n0 = blockIdx.x * 32, k0 = blockIdx.y * 32;
  int tx = threadIdx.x & 31, ty = threadIdx.x >> 5;
  #pragma unroll
  for (int i = 0; i < 32; i += 8)
    t[ty + i][tx] = src[(k0 + ty + i) * D_MODEL + n0 + tx];
  __syncthreads();
  #pragma unroll
  for (int i = 0; i < 32; i += 8)
    dst[(size_t)(n0 + ty + i) * D_MODEL + k0 + tx] = f2bf(t[tx][ty + i]);
}

// ---------------- prep: log2(weights + 1e-20) - 16 (fixed-max softmax bias) ----------------
extern "C" __global__ void __launch_bounds__(256) klw(
    const float* __restrict__ w, float* __restrict__ lw)
{
  int i = blockIdx.x * 256 + threadIdx.x;
  if (i < BB * SS) lw[i] = log2f(w[i] + 1e-20f) - 16.0f;
}

// ---------------- V transpose: (b,h,s,dk) -> (b,h,dk,s) ----------------
extern "C" __global__ void __launch_bounds__(256) ktrans_v(
    const u16* __restrict__ src, u16* __restrict__ dst)
{
  __shared__ u16 T[64][72];
  int bh = blockIdx.y; int s0 = blockIdx.x * 64;
  int tid = threadIdx.x;
  int r = tid >> 3, c = (tid & 7) * 8;
  #pragma unroll
  for (int i = 0; i < 2; ++i)
    *(bf16x8*)&T[r + i * 32][c] = *(const bf16x8*)&src[((size_t)bh * SS + s0 + r + i * 32) * DKD + c];
  __syncthreads();
  #pragma unroll
  for (int i = 0; i < 2; ++i) {
    int dk = r + i * 32;
    ushort4 o0, o1;
    o0.x = T[c + 0][dk]; o0.y = T[c + 1][dk]; o0.z = T[c + 2][dk]; o0.w = T[c + 3][dk];
    o1.x = T[c + 4][dk]; o1.y = T[c + 5][dk]; o1.z = T[c + 6][dk]; o1.w = T[c + 7][dk];
    *(ushort4*)&dst[((size_t)bh * DKD + dk) * SS + s0 + c] = o0;
    *(ushort4*)&dst[((size_t)bh * DKD + dk) * SS + s0 + c + 4] = o1;
  }
}

// ---------------- shared GEMM core: C(128x128) = A(128xK) * Bt(128xK)^T ----------------
__device__ __forceinline__ void gemm_tile(const u16* __restrict__ Ag, const u16* __restrict__ Bg,
                                          u16* As, u16* Bs, f32x4 acc[4][4], int tid)
{
  int lane = tid & 63;
  int lr = lane & 15, lg = lane >> 4;
  int w = tid >> 6, wr = w >> 1, wc = w & 1;
  for (int k0 = 0; k0 < D_MODEL; k0 += 32) {
    #pragma unroll
    for (int c = 0; c < 2; ++c) {
      int idx = tid + c * 256;
      int row = idx >> 2, col = (idx & 3) * 8;
      gld16(Ag + row * D_MODEL + k0 + col, As + idx * 8);
      gld16(Bg + row * D_MODEL + k0 + col, Bs + idx * 8);
    }
    __syncthreads();
    bf16x8 af[4], bfr[4];
    #pragma unroll
    for (int mi = 0; mi < 4; ++mi)
      af[mi] = *(const bf16x8*)(As + (wr * 64 + mi * 16 + lr) * 32 + lg * 8);
    #pragma unroll
    for (int nj = 0; nj < 4; ++nj)
      bfr[nj] = *(const bf16x8*)(Bs + (wc * 64 + nj * 16 + lr) * 32 + lg * 8);
    #pragma unroll
    for (int mi = 0; mi < 4; ++mi)
      #pragma unroll
      for (int nj = 0; nj < 4; ++nj)
        acc[mi][nj] = __builtin_amdgcn_mfma_f32_16x16x32_bf16(af[mi], bfr[nj], acc[mi][nj], 0, 0, 0);
    __syncthreads();
  }
}

// ---------------- fused QKV projection ----------------
// z==0: Q scaled by QSCL. All outputs layout (b,h,s,dk).
extern "C" __global__ void __launch_bounds__(256) kgemm_qkv(
    const u16* __restrict__ xq, const u16* __restrict__ xk, const u16* __restrict__ xv,
    const u16* __restrict__ wqt, const u16* __restrict__ wkt, const u16* __restrict__ wvt,
    const float* __restrict__ bq, const float* __restrict__ bk, const float* __restrict__ bv,
    u16* __restrict__ Qb, u16* __restrict__ Kb, u16* __restrict__ Vb)
{
  __shared__ u16 As[128 * 32], Bs[128 * 32];
  int z = blockIdx.z;
  const u16* X  = z == 0 ? xq : (z == 1 ? xk : xv);
  const u16* Wt = z == 0 ? wqt : (z == 1 ? wkt : wvt);
  const float* bias = z == 0 ? bq : (z == 1 ? bk : bv);
  u16* dst = z == 0 ? Qb : (z == 1 ? Kb : Vb);
  int tid = threadIdx.x;
  f32x4 zero = {0.f, 0.f, 0.f, 0.f};
  f32x4 acc[4][4];
  #pragma unroll
  for (int i = 0; i < 4; ++i)
    #pragma unroll
    for (int j = 0; j < 4; ++j) acc[i][j] = zero;
  int m0 = blockIdx.y * 128, n0 = blockIdx.x * 128;
  gemm_tile(X + (size_t)m0 * D_MODEL, Wt + (size_t)n0 * D_MODEL, As, Bs, acc, tid);
  int lane = tid & 63, lr = lane & 15, lg = lane >> 4;
  int w = tid >> 6, wr = w >> 1, wc = w & 1;
  float scl = (z == 0) ? QSCL : 1.0f;
  #pragma unroll
  for (int mi = 0; mi < 4; ++mi)
    #pragma unroll
    for (int nj = 0; nj < 4; ++nj) {
      int n = n0 + wc * 64 + nj * 16 + lr;
      float bs = bias[n];
      int h = n >> 6, dk = n & 63;
      #pragma unroll
      for (int j = 0; j < 4; ++j) {
        int m = m0 + wr * 64 + mi * 16 + lg * 4 + j;
        int b = m >> 11, s = m & 2047;
        dst[(((size_t)(b * NH + h)) * SS + s) * DKD + dk] = f2bf((acc[mi][nj][j] + bs) * scl);
      }
    }
}

// ---------------- output projection ----------------
extern "C" __global__ void __launch_bounds__(256) kgemm_o(
    const u16* __restrict__ AO, const u16* __restrict__ wot,
    const float* __restrict__ bo, float* __restrict__ out)
{
  __shared__ u16 As[128 * 32], Bs[128 * 32];
  int tid = threadIdx.x;
  f32x4 zero = {0.f, 0.f, 0.f, 0.f};
  f32x4 acc[4][4];
  #pragma unroll
  for (int i = 0; i < 4; ++i)
    #pragma unroll
    for (int j = 0; j < 4; ++j) acc[i][j] = zero;
  int m0 = blockIdx.y * 128, n0 = blockIdx.x * 128;
  gemm_tile(AO + (size_t)m0 * D_MODEL, wot + (size_t)n0 * D_MODEL, As, Bs, acc, tid);
  int lane = tid & 63, lr = lane & 15, lg = lane >> 4;
  int w = tid >> 6, wr = w >> 1, wc = w & 1;
  #pragma unroll
  for (int mi = 0; mi < 4; ++mi)
    #pragma unroll
    for (int nj = 0; nj < 4; ++nj) {
      int n = n0 + wc * 64 + nj * 16 + lr;
      float bs = bo[n];
      #pragma unroll
      for (int j = 0; j < 4; ++j) {
        int m = m0 + wr * 64 + mi * 16 + lg * 4 + j;
        out[(size_t)m * D_MODEL + n] = acc[mi][nj][j] + bs;
      }
    }
}

// ---------------- flash attention: 4 waves x 32q, dbuf prefetch, fixed-max softmax ----------------
// Qb: (b,h,s,dk) bf16 PRE-SCALED by log2(e)/8. Kb: (b,h,s,dk). Vt: (b,h,dk,s).
// lw2: (b,s) f32 = log2(w+1e-20)-16. AO: (b,s,1024) bf16.
// Per block: 128 q rows, 4 waves x 32q (two 16-col B-fragments). St = K*Q^T with
// accumulator INITIALIZED to log-weights; p = exp2(st); O^T = V^T * P^T.
// lsum via MFMA with all-ones A-fragment: every lane ends with full denominator for q=lane&15.
extern "C" __global__ void __launch_bounds__(256, 3) kattn(
    const u16* __restrict__ Qb, const u16* __restrict__ Kb, const u16* __restrict__ Vt,
    const float* __restrict__ lw2, u16* __restrict__ AO)
{
  __shared__ __align__(16) u16 Ks[2][64 * 64];
  __shared__ __align__(16) u16 Vs[2][64 * 64];
  __shared__ __align__(16) unsigned Pt[4][2][16 * 36];  // [wave][qm][q=16 rows x 36-word stride]

  int tid = threadIdx.x, lane = tid & 63, w = tid >> 6;  // w 0..3
  int lr = lane & 15, lg = lane >> 4;
  int bh = blockIdx.y, b = bh >> 4, h = bh & 15;
  int q0 = blockIdx.x * 128;

  const u16* Qg = Qb + ((size_t)bh * SS + q0 + w * 32) * DKD;
  const u16* Kg = Kb + (size_t)bh * SS * DKD;
  const u16* Vg = Vt + (size_t)bh * DKD * SS;   // rows = dk, cols = s
  const float* lwb = lw2 + b * SS;

  // Q B-fragments: col = q = qm*16+lr, k-elems = ki*32 + lg*8..+7
  bf16x8 qf[2][2];
  #pragma unroll
  for (int qm = 0; qm < 2; ++qm) {
    qf[qm][0] = *(const bf16x8*)(Qg + (qm * 16 + lr) * DKD + lg * 8);
    qf[qm][1] = *(const bf16x8*)(Qg + (qm * 16 + lr) * DKD + 32 + lg * 8);
  }

  // all-ones bf16 A-fragment for the lsum MFMA
  union { u16 s[8]; bf16x8 v; } onesu;
  #pragma unroll
  for (int i = 0; i < 8; ++i) onesu.s[i] = 0x3F80;
  bf16x8 onesv = onesu.v;

  f32x4 zero = {0.f, 0.f, 0.f, 0.f};
  f32x4 acco[2][4] = {{zero, zero, zero, zero}, {zero, zero, zero, zero}};
  f32x4 acc_l[2] = {zero, zero};

  // staging: 256 threads; chunks idx=tid (rows 0..31) and idx=tid+256 (rows 32..63)
  // LDS[row][c3] = Global[row][c3 ^ (row&7)]  (linear dest for gld16; swizzle on src+read)
  int srow0 = tid >> 3, sc0 = ((tid & 7) ^ (srow0 & 7)) * 8;
  int srow1 = srow0 + 32, sc1 = ((tid & 7) ^ (srow1 & 7)) * 8;

#define STAGE(t, bi) do { \
    gld16(Kg + (size_t)((t) * 64 + srow0) * DKD + sc0, &Ks[bi][tid * 8]); \
    gld16(Kg + (size_t)((t) * 64 + srow1) * DKD + sc1, &Ks[bi][(tid + 256) * 8]); \
    gld16(Vg + (size_t)srow0 * SS + (t) * 64 + sc0, &Vs[bi][tid * 8]); \
    gld16(Vg + (size_t)srow1 * SS + (t) * 64 + sc1, &Vs[bi][(tid + 256) * 8]); \
  } while (0)

  STAGE(0, 0);
  for (int t = 0; t < SS / 64; ++t) {
    __syncthreads();                    // drains vmcnt: buf[t&1] ready; prev reads done
    if (t + 1 < SS / 64) STAGE(t + 1, (t + 1) & 1);
    int bi = t & 1;
    int kv0 = t * 64;

    // ---- St = lw + K * Q^T : St[kv = nk*16 + lg*4 + j][q = qm*16 + lr] ----
    f32x4 st[2][4];
    #pragma unroll
    for (int nk = 0; nk < 4; ++nk) {
      float4 l4 = *(const float4*)(lwb + kv0 + nk * 16 + lg * 4);
      f32x4 iv = {l4.x, l4.y, l4.z, l4.w};
      st[0][nk] = iv; st[1][nk] = iv;
    }
    __builtin_amdgcn_s_setprio(1);
    #pragma unroll
    for (int ki = 0; ki < 2; ++ki) {
      bf16x8 kf[4];
      #pragma unroll
      for (int nk = 0; nk < 4; ++nk)
        kf[nk] = *(const bf16x8*)&Ks[bi][(nk * 16 + lr) * 64 + (((ki * 4 + lg) ^ (lr & 7)) * 8)];
      #pragma unroll
      for (int qm = 0; qm < 2; ++qm)
        #pragma unroll
        for (int nk = 0; nk < 4; ++nk)
          st[qm][nk] = __builtin_amdgcn_mfma_f32_16x16x32_bf16(kf[nk], qf[qm][ki], st[qm][nk], 0, 0, 0);
    }
    __builtin_amdgcn_s_setprio(0);

    // ---- p = exp2(st); pack to Pt (no scalar lsum: summed by ones-MFMA below) ----
    #pragma unroll
    for (int qm = 0; qm < 2; ++qm)
      #pragma unroll
      for (int nk = 0; nk < 4; ++nk) {
        float p0 = exp2f(st[qm][nk][0]);
        float p1 = exp2f(st[qm][nk][1]);
        float p2 = exp2f(st[qm][nk][2]);
        float p3 = exp2f(st[qm][nk][3]);
        union { unsigned u; __bf16 b2[2]; } c0, c1;
        c0.b2[0] = (__bf16)p0; c0.b2[1] = (__bf16)p1;
        c1.b2[0] = (__bf16)p2; c1.b2[1] = (__bf16)p3;
        *(uint2*)&Pt[w][qm][lr * 36 + nk * 8 + lg * 2] = make_uint2(c0.u, c1.u);
      }

    // ---- O^T += V^T * P^T ; lsum += ones * P^T (Pt wave-private; same-wave DS ordering) ----
    __builtin_amdgcn_s_setprio(1);
    #pragma unroll
    for (int ks = 0; ks < 2; ++ks) {
      bf16x8 vf[4];
      #pragma unroll
      for (int dn = 0; dn < 4; ++dn)
        vf[dn] = *(const bf16x8*)&Vs[bi][(dn * 16 + lr) * 64 + (((ks * 4 + lg) ^ (lr & 7)) * 8)];
      #pragma unroll
      for (int qm = 0; qm < 2; ++qm) {
        bf16x8 F = *(const bf16x8*)&Pt[w][qm][lr * 36 + ks * 16 + lg * 4];
        acc_l[qm] = __builtin_amdgcn_mfma_f32_16x16x32_bf16(onesv, F, acc_l[qm], 0, 0, 0);
        #pragma unroll
        for (int dn = 0; dn < 4; ++dn)
          acco[qm][dn] = __builtin_amdgcn_mfma_f32_16x16x32_bf16(vf[dn], F, acco[qm][dn], 0, 0, 0);
      }
    }
    __builtin_amdgcn_s_setprio(0);
  }
#undef STAGE

  // ---- epilogue: every lane holds full lsum(q=lr) in acc_l[qm][*]; normalize, store ----
  #pragma unroll
  for (int qm = 0; qm < 2; ++qm) {
    float inv = 1.0f / acc_l[qm][0];
    int s = q0 + w * 32 + qm * 16 + lr;
    size_t base = ((size_t)b * SS + s) * D_MODEL + h * DKD;
    #pragma unroll
    for (int dn = 0; dn < 4; ++dn) {
      ushort4 o;
      o.x = f2bf(acco[qm][dn][0] * inv);
      o.y = f2bf(acco[qm][dn][1] * inv);
      o.z = f2bf(acco[qm][dn][2] * inv);
      o.w = f2bf(acco[qm][dn][3] * inv);
      *(ushort4*)(AO + base + dn * 16 + lg * 4) = o;
    }
  }
}

extern "C" void kernel_launch(void* const* d_in, const int* in_sizes, int n_in,
                              void* d_out, int out_size, void* d_ws, size_t ws_size,
                              hipStream_t stream) {
  const float* query = (const float*)d_in[0];
  const float* key_  = (const float*)d_in[1];
  const float* value = (const float*)d_in[2];
  const float* wts   = (const float*)d_in[3];
  const float* wq = (const float*)d_in[4];
  const float* bq = (const float*)d_in[5];
  const float* wk = (const float*)d_in[6];
  const float* bk = (const float*)d_in[7];
  const float* wv = (const float*)d_in[8];
  const float* bv = (const float*)d_in[9];
  const float* wo = (const float*)d_in[10];
  const float* bo = (const float*)d_in[11];
  float* out = (float*)d_out;

  char* ws = (char*)d_ws;
  const size_t MB = 1024 * 1024;
  u16* Xq  = (u16*)(ws + 0 * MB);
  u16* Xk  = (u16*)(ws + 8 * MB);
  u16* Xv  = (u16*)(ws + 16 * MB);   // dead after kgemm_qkv; reused as VtT
  u16* WqT = (u16*)(ws + 24 * MB);
  u16* WkT = (u16*)(ws + 26 * MB);
  u16* WvT = (u16*)(ws + 28 * MB);
  u16* WoT = (u16*)(ws + 30 * MB);
  u16* Qb  = (u16*)(ws + 32 * MB);
  u16* Kb  = (u16*)(ws + 40 * MB);
  u16* Vb  = (u16*)(ws + 48 * MB);
  u16* AO  = (u16*)(ws + 56 * MB);
  float* lwbuf = (float*)(ws + 64 * MB);
  u16* VtT = (u16*)(ws + 16 * MB);   // V transposed (b,h,dk,s), overwrites Xv after use

  kprep_conv<<<dim3(4096, 3), 256, 0, stream>>>(query, key_, value, Xq, Xk, Xv);
  kprep_wt<<<dim3(32, 32, 4), 256, 0, stream>>>(wq, wk, wv, wo, WqT, WkT, WvT, WoT);
  klw<<<16, 256, 0, stream>>>(wts, lwbuf);
  kgemm_qkv<<<dim3(8, 32, 3), 256, 0, stream>>>(Xq, Xk, Xv, WqT, WkT, WvT, bq, bk, bv, Qb, Kb, Vb);
  ktrans_v<<<dim3(32, 32), 256, 0, stream>>>(Vb, VtT);
  kattn<<<dim3(16, 32), 256, 0, stream>>>(Qb, Kb, VtT, lwbuf, AO);
  kgemm_o<<<dim3(8, 32), 256, 0, stream>>>(AO, WoT, bo, out);
}

// Round 6
// 153.012 us; speedup vs baseline: 1.2143x; 1.0226x over previous
//
#include <hip/hip_runtime.h>

typedef unsigned short u16;
typedef __bf16 bf16x8 __attribute__((ext_vector_type(8)));
typedef float f32x4 __attribute__((ext_vector_type(4)));

#define D_MODEL 1024
#define NH 16
#define DKD 64
#define BB 2
#define SS 2048
// log2(e)/8: folded into Q at projection time
#define QSCL 0.18033688011112042f

__device__ __forceinline__ u16 f2bf(float f) {
  union { float f; unsigned u; } x; x.f = f;
  unsigned r = x.u + 0x7fffu + ((x.u >> 16) & 1u);
  return (u16)(r >> 16);
}

__device__ __forceinline__ void gld16(const u16* g, u16* l) {
  __builtin_amdgcn_global_load_lds((__attribute__((address_space(1))) void*)(g),
                                   (__attribute__((address_space(3))) void*)(l),
                                   16, 0, 0);
}

// ---------------- prep: fp32 -> bf16 activation convert ----------------
extern "C" __global__ void __launch_bounds__(256) kprep_conv(
    const float* __restrict__ q, const float* __restrict__ k, const float* __restrict__ v,
    u16* __restrict__ xq, u16* __restrict__ xk, u16* __restrict__ xv)
{
  int z = blockIdx.y;
  const float* s = z == 0 ? q : (z == 1 ? k : v);
  u16* d = z == 0 ? xq : (z == 1 ? xk : xv);
  int i = (blockIdx.x * 256 + threadIdx.x) * 4;
  float4 val = *(const float4*)(s + i);
  ushort4 o;
  o.x = f2bf(val.x); o.y = f2bf(val.y); o.z = f2bf(val.z); o.w = f2bf(val.w);
  *(ushort4*)(d + i) = o;
}

// ---------------- prep: weight transpose + bf16 convert ----------------
extern "C" __global__ void __launch_bounds__(256) kprep_wt(
    const float* __restrict__ w0, const float* __restrict__ w1,
    const float* __restrict__ w2, const float* __restrict__ w3,
    u16* __restrict__ o0, u16* __restrict__ o1, u16* __restrict__ o2, u16* __restrict__ o3)
{
  const float* src; u16* dst;
  switch (blockIdx.z) {
    case 0: src = w0; dst = o0; break;
    case 1: src = w1; dst = o1; break;
    case 2: src = w2; dst = o2; break;
    default: src = w3; dst = o3; break;
  }
  __shared__ float t[32][33];
  int n0 = blockIdx.x * 32, k0 = blockIdx.y * 32;
  int tx = threadIdx.x & 31, ty = threadIdx.x >> 5;
  #pragma unroll
  for (int i = 0; i < 32; i += 8)
    t[ty + i][tx] = src[(k0 + ty + i) * D_MODEL + n0 + tx];
  __syncthreads();
  #pragma unroll
  for (int i = 0; i < 32; i += 8)
    dst[(size_t)(n0 + ty + i) * D_MODEL + k0 + tx] = f2bf(t[tx][ty + i]);
}

// ---------------- prep: log2(weights + 1e-20) - 16 (fixed-max softmax bias) ----------------
extern "C" __global__ void __launch_bounds__(256) klw(
    const float* __restrict__ w, float* __restrict__ lw)
{
  int i = blockIdx.x * 256 + threadIdx.x;
  if (i < BB * SS) lw[i] = log2f(w[i] + 1e-20f) - 16.0f;
}

// ---------------- V transpose: (b,h,s,dk) -> (b,h,dk,s) ----------------
extern "C" __global__ void __launch_bounds__(256) ktrans_v(
    const u16* __restrict__ src, u16* __restrict__ dst)
{
  __shared__ u16 T[64][72];
  int bh = blockIdx.y; int s0 = blockIdx.x * 64;
  int tid = threadIdx.x;
  int r = tid >> 3, c = (tid & 7) * 8;
  #pragma unroll
  for (int i = 0; i < 2; ++i)
    *(bf16x8*)&T[r + i * 32][c] = *(const bf16x8*)&src[((size_t)bh * SS + s0 + r + i * 32) * DKD + c];
  __syncthreads();
  #pragma unroll
  for (int i = 0; i < 2; ++i) {
    int dk = r + i * 32;
    ushort4 o0, o1;
    o0.x = T[c + 0][dk]; o0.y = T[c + 1][dk]; o0.z = T[c + 2][dk]; o0.w = T[c + 3][dk];
    o1.x = T[c + 4][dk]; o1.y = T[c + 5][dk]; o1.z = T[c + 6][dk]; o1.w = T[c + 7][dk];
    *(ushort4*)&dst[((size_t)bh * DKD + dk) * SS + s0 + c] = o0;
    *(ushort4*)&dst[((size_t)bh * DKD + dk) * SS + s0 + c + 4] = o1;
  }
}

// ---------------- shared GEMM core: C(128x128) = A(128xK) * Bt(128xK)^T ----------------
__device__ __forceinline__ void gemm_tile(const u16* __restrict__ Ag, const u16* __restrict__ Bg,
                                          u16* As, u16* Bs, f32x4 acc[4][4], int tid)
{
  int lane = tid & 63;
  int lr = lane & 15, lg = lane >> 4;
  int w = tid >> 6, wr = w >> 1, wc = w & 1;
  for (int k0 = 0; k0 < D_MODEL; k0 += 32) {
    #pragma unroll
    for (int c = 0; c < 2; ++c) {
      int idx = tid + c * 256;
      int row = idx >> 2, col = (idx & 3) * 8;
      gld16(Ag + row * D_MODEL + k0 + col, As + idx * 8);
      gld16(Bg + row * D_MODEL + k0 + col, Bs + idx * 8);
    }
    __syncthreads();
    bf16x8 af[4], bfr[4];
    #pragma unroll
    for (int mi = 0; mi < 4; ++mi)
      af[mi] = *(const bf16x8*)(As + (wr * 64 + mi * 16 + lr) * 32 + lg * 8);
    #pragma unroll
    for (int nj = 0; nj < 4; ++nj)
      bfr[nj] = *(const bf16x8*)(Bs + (wc * 64 + nj * 16 + lr) * 32 + lg * 8);
    #pragma unroll
    for (int mi = 0; mi < 4; ++mi)
      #pragma unroll
      for (int nj = 0; nj < 4; ++nj)
        acc[mi][nj] = __builtin_amdgcn_mfma_f32_16x16x32_bf16(af[mi], bfr[nj], acc[mi][nj], 0, 0, 0);
    __syncthreads();
  }
}

// ---------------- fused QKV projection ----------------
// z==0: Q scaled by QSCL. All outputs layout (b,h,s,dk).
extern "C" __global__ void __launch_bounds__(256) kgemm_qkv(
    const u16* __restrict__ xq, const u16* __restrict__ xk, const u16* __restrict__ xv,
    const u16* __restrict__ wqt, const u16* __restrict__ wkt, const u16* __restrict__ wvt,
    const float* __restrict__ bq, const float* __restrict__ bk, const float* __restrict__ bv,
    u16* __restrict__ Qb, u16* __restrict__ Kb, u16* __restrict__ Vb)
{
  __shared__ u16 As[128 * 32], Bs[128 * 32];
  int z = blockIdx.z;
  const u16* X  = z == 0 ? xq : (z == 1 ? xk : xv);
  const u16* Wt = z == 0 ? wqt : (z == 1 ? wkt : wvt);
  const float* bias = z == 0 ? bq : (z == 1 ? bk : bv);
  u16* dst = z == 0 ? Qb : (z == 1 ? Kb : Vb);
  int tid = threadIdx.x;
  f32x4 zero = {0.f, 0.f, 0.f, 0.f};
  f32x4 acc[4][4];
  #pragma unroll
  for (int i = 0; i < 4; ++i)
    #pragma unroll
    for (int j = 0; j < 4; ++j) acc[i][j] = zero;
  int m0 = blockIdx.y * 128, n0 = blockIdx.x * 128;
  gemm_tile(X + (size_t)m0 * D_MODEL, Wt + (size_t)n0 * D_MODEL, As, Bs, acc, tid);
  int lane = tid & 63, lr = lane & 15, lg = lane >> 4;
  int w = tid >> 6, wr = w >> 1, wc = w & 1;
  float scl = (z == 0) ? QSCL : 1.0f;
  #pragma unroll
  for (int mi = 0; mi < 4; ++mi)
    #pragma unroll
    for (int nj = 0; nj < 4; ++nj) {
      int n = n0 + wc * 64 + nj * 16 + lr;
      float bs = bias[n];
      int h = n >> 6, dk = n & 63;
      #pragma unroll
      for (int j = 0; j < 4; ++j) {
        int m = m0 + wr * 64 + mi * 16 + lg * 4 + j;
        int b = m >> 11, s = m & 2047;
        dst[(((size_t)(b * NH + h)) * SS + s) * DKD + dk] = f2bf((acc[mi][nj][j] + bs) * scl);
      }
    }
}

// ---------------- output projection ----------------
extern "C" __global__ void __launch_bounds__(256) kgemm_o(
    const u16* __restrict__ AO, const u16* __restrict__ wot,
    const float* __restrict__ bo, float* __restrict__ out)
{
  __shared__ u16 As[128 * 32], Bs[128 * 32];
  int tid = threadIdx.x;
  f32x4 zero = {0.f, 0.f, 0.f, 0.f};
  f32x4 acc[4][4];
  #pragma unroll
  for (int i = 0; i < 4; ++i)
    #pragma unroll
    for (int j = 0; j < 4; ++j) acc[i][j] = zero;
  int m0 = blockIdx.y * 128, n0 = blockIdx.x * 128;
  gemm_tile(AO + (size_t)m0 * D_MODEL, wot + (size_t)n0 * D_MODEL, As, Bs, acc, tid);
  int lane = tid & 63, lr = lane & 15, lg = lane >> 4;
  int w = tid >> 6, wr = w >> 1, wc = w & 1;
  #pragma unroll
  for (int mi = 0; mi < 4; ++mi)
    #pragma unroll
    for (int nj = 0; nj < 4; ++nj) {
      int n = n0 + wc * 64 + nj * 16 + lr;
      float bs = bo[n];
      #pragma unroll
      for (int j = 0; j < 4; ++j) {
        int m = m0 + wr * 64 + mi * 16 + lg * 4 + j;
        out[(size_t)m * D_MODEL + n] = acc[mi][nj][j] + bs;
      }
    }
}

// ---------------- flash attention: 4 waves x 32q, 3-buf counted-vmcnt, XCD-clustered ----------------
// Qb: (b,h,s,dk) bf16 PRE-SCALED by log2(e)/8. Kb: (b,h,s,dk). Vt: (b,h,dk,s).
// lw2: (b,s) f32 = log2(w+1e-20)-16 (staged to LDS once). AO: (b,s,1024) bf16.
// St = lw + K*Q^T; p = exp2(st); O^T = V^T*P^T; lsum via ones-MFMA.
// Pipeline: triple-buffered K/V, prefetch depth 2, raw s_barrier + s_waitcnt vmcnt(4)
// (vmcnt counts: 4 gld16/STAGE, 8 in flight steady-state, oldest 4 = current tile).
extern "C" __global__ void __launch_bounds__(256, 2) kattn(
    const u16* __restrict__ Qb, const u16* __restrict__ Kb, const u16* __restrict__ Vt,
    const float* __restrict__ lw2, u16* __restrict__ AO)
{
  __shared__ __align__(16) u16 Ks[3][64 * 64];
  __shared__ __align__(16) u16 Vs[3][64 * 64];
  __shared__ __align__(16) unsigned Pt[4][2][16 * 36];  // [wave][qm][q=16 rows x 36-word stride]
  __shared__ __align__(16) float lwf[SS];               // whole lw row for this batch

  int tid = threadIdx.x, lane = tid & 63, w = tid >> 6;  // w 0..3
  int lr = lane & 15, lg = lane >> 4;

  // XCD-clustered decode: xcd = wgid&7 (m09 round-robin). Each XCD owns 4 heads
  // (bh = xcd + 8*g) x all 16 q-tiles -> K/V working set 2MB, L2-resident.
  int n = blockIdx.x;                  // 0..511
  int xcd = n & 7, slot = n >> 3;      // 64 slots per XCD
  int bh = xcd + 8 * (slot >> 4);      // 4 heads per XCD
  int q0 = (slot & 15) * 128;
  int b = bh >> 4, h = bh & 15;

  const u16* Qg = Qb + ((size_t)bh * SS + q0 + w * 32) * DKD;
  const u16* Kg = Kb + (size_t)bh * SS * DKD;
  const u16* Vg = Vt + (size_t)bh * DKD * SS;   // rows = dk, cols = s
  const float* lwb = lw2 + b * SS;

  // stage lw row into LDS (keeps per-tile score-bias off the vmcnt queue)
  #pragma unroll
  for (int i = 0; i < 2; ++i) {
    int idx = tid + i * 256;           // 512 float4 total
    *(float4*)&lwf[idx * 4] = *(const float4*)(lwb + idx * 4);
  }

  // Q B-fragments: col = q = qm*16+lr, k-elems = ki*32 + lg*8..+7
  bf16x8 qf[2][2];
  #pragma unroll
  for (int qm = 0; qm < 2; ++qm) {
    qf[qm][0] = *(const bf16x8*)(Qg + (qm * 16 + lr) * DKD + lg * 8);
    qf[qm][1] = *(const bf16x8*)(Qg + (qm * 16 + lr) * DKD + 32 + lg * 8);
  }

  // all-ones bf16 A-fragment for the lsum MFMA
  union { u16 s[8]; bf16x8 v; } onesu;
  #pragma unroll
  for (int i = 0; i < 8; ++i) onesu.s[i] = 0x3F80;
  bf16x8 onesv = onesu.v;

  f32x4 zero = {0.f, 0.f, 0.f, 0.f};
  f32x4 acco[2][4] = {{zero, zero, zero, zero}, {zero, zero, zero, zero}};
  f32x4 acc_l[2] = {zero, zero};

  // staging: 256 threads; chunks idx=tid (rows 0..31) and idx=tid+256 (rows 32..63)
  // LDS[row][c3] = Global[row][c3 ^ (row&7)]  (linear dest for gld16; swizzle on src+read)
  int srow0 = tid >> 3, sc0 = ((tid & 7) ^ (srow0 & 7)) * 8;
  int srow1 = srow0 + 32, sc1 = ((tid & 7) ^ (srow1 & 7)) * 8;

#define STAGE(t, bi) do { \
    gld16(Kg + (size_t)((t) * 64 + srow0) * DKD + sc0, &Ks[bi][tid * 8]); \
    gld16(Kg + (size_t)((t) * 64 + srow1) * DKD + sc1, &Ks[bi][(tid + 256) * 8]); \
    gld16(Vg + (size_t)srow0 * SS + (t) * 64 + sc0, &Vs[bi][tid * 8]); \
    gld16(Vg + (size_t)srow1 * SS + (t) * 64 + sc1, &Vs[bi][(tid + 256) * 8]); \
  } while (0)

  const int NT = SS / 64;
  STAGE(0, 0);
  STAGE(1, 1);
  for (int t = 0; t < NT; ++t) {
    // buf[t%3] ready when this wave's tile-t loads (oldest 4 of <=8 in flight) retire.
    // lgkmcnt(0): lw ds_writes (t=0) / Pt same-wave ordering are already drained -> free.
    if (t < NT - 1) asm volatile("s_waitcnt vmcnt(4) lgkmcnt(0)" ::: "memory");
    else            asm volatile("s_waitcnt vmcnt(0) lgkmcnt(0)" ::: "memory");
    __builtin_amdgcn_s_barrier();
    __builtin_amdgcn_sched_barrier(0);
    if (t + 2 < NT) STAGE(t + 2, (t + 2) % 3);
    int bi = t % 3;
    int kv0 = t * 64;

    // ---- St = lw + K * Q^T : St[kv = nk*16 + lg*4 + j][q = qm*16 + lr] ----
    f32x4 st[2][4];
    #pragma unroll
    for (int nk = 0; nk < 4; ++nk) {
      f32x4 iv = *(const f32x4*)&lwf[kv0 + nk * 16 + lg * 4];
      st[0][nk] = iv; st[1][nk] = iv;
    }
    __builtin_amdgcn_s_setprio(1);
    #pragma unroll
    for (int ki = 0; ki < 2; ++ki) {
      bf16x8 kf[4];
      #pragma unroll
      for (int nk = 0; nk < 4; ++nk)
        kf[nk] = *(const bf16x8*)&Ks[bi][(nk * 16 + lr) * 64 + (((ki * 4 + lg) ^ (lr & 7)) * 8)];
      #pragma unroll
      for (int qm = 0; qm < 2; ++qm)
        #pragma unroll
        for (int nk = 0; nk < 4; ++nk)
          st[qm][nk] = __builtin_amdgcn_mfma_f32_16x16x32_bf16(kf[nk], qf[qm][ki], st[qm][nk], 0, 0, 0);
    }
    __builtin_amdgcn_s_setprio(0);

    // ---- p = exp2(st); pack to Pt (lsum summed by ones-MFMA below) ----
    #pragma unroll
    for (int qm = 0; qm < 2; ++qm)
      #pragma unroll
      for (int nk = 0; nk < 4; ++nk) {
        float p0 = exp2f(st[qm][nk][0]);
        float p1 = exp2f(st[qm][nk][1]);
        float p2 = exp2f(st[qm][nk][2]);
        float p3 = exp2f(st[qm][nk][3]);
        union { unsigned u; __bf16 b2[2]; } c0, c1;
        c0.b2[0] = (__bf16)p0; c0.b2[1] = (__bf16)p1;
        c1.b2[0] = (__bf16)p2; c1.b2[1] = (__bf16)p3;
        *(uint2*)&Pt[w][qm][lr * 36 + nk * 8 + lg * 2] = make_uint2(c0.u, c1.u);
      }

    // ---- O^T += V^T * P^T ; lsum += ones * P^T (Pt wave-private; same-wave DS ordering) ----
    __builtin_amdgcn_s_setprio(1);
    #pragma unroll
    for (int ks = 0; ks < 2; ++ks) {
      bf16x8 vf[4];
      #pragma unroll
      for (int dn = 0; dn < 4; ++dn)
        vf[dn] = *(const bf16x8*)&Vs[bi][(dn * 16 + lr) * 64 + (((ks * 4 + lg) ^ (lr & 7)) * 8)];
      #pragma unroll
      for (int qm = 0; qm < 2; ++qm) {
        bf16x8 F = *(const bf16x8*)&Pt[w][qm][lr * 36 + ks * 16 + lg * 4];
        acc_l[qm] = __builtin_amdgcn_mfma_f32_16x16x32_bf16(onesv, F, acc_l[qm], 0, 0, 0);
        #pragma unroll
        for (int dn = 0; dn < 4; ++dn)
          acco[qm][dn] = __builtin_amdgcn_mfma_f32_16x16x32_bf16(vf[dn], F, acco[qm][dn], 0, 0, 0);
      }
    }
    __builtin_amdgcn_s_setprio(0);
  }
#undef STAGE

  // ---- epilogue: every lane holds full lsum(q=lr) in acc_l[qm][*]; normalize, store ----
  #pragma unroll
  for (int qm = 0; qm < 2; ++qm) {
    float inv = 1.0f / acc_l[qm][0];
    int s = q0 + w * 32 + qm * 16 + lr;
    size_t base = ((size_t)b * SS + s) * D_MODEL + h * DKD;
    #pragma unroll
    for (int dn = 0; dn < 4; ++dn) {
      ushort4 o;
      o.x = f2bf(acco[qm][dn][0] * inv);
      o.y = f2bf(acco[qm][dn][1] * inv);
      o.z = f2bf(acco[qm][dn][2] * inv);
      o.w = f2bf(acco[qm][dn][3] * inv);
      *(ushort4*)(AO + base + dn * 16 + lg * 4) = o;
    }
  }
}

extern "C" void kernel_launch(void* const* d_in, const int* in_sizes, int n_in,
                              void* d_out, int out_size, void* d_ws, size_t ws_size,
                              hipStream_t stream) {
  const float* query = (const float*)d_in[0];
  const float* key_  = (const float*)d_in[1];
  const float* value = (const float*)d_in[2];
  const float* wts   = (const float*)d_in[3];
  const float* wq = (const float*)d_in[4];
  const float* bq = (const float*)d_in[5];
  const float* wk = (const float*)d_in[6];
  const float* bk = (const float*)d_in[7];
  const float* wv = (const float*)d_in[8];
  const float* bv = (const float*)d_in[9];
  const float* wo = (const float*)d_in[10];
  const float* bo = (const float*)d_in[11];
  float* out = (float*)d_out;

  char* ws = (char*)d_ws;
  const size_t MB = 1024 * 1024;
  u16* Xq  = (u16*)(ws + 0 * MB);
  u16* Xk  = (u16*)(ws + 8 * MB);
  u16* Xv  = (u16*)(ws + 16 * MB);   // dead after kgemm_qkv; reused as VtT
  u16* WqT = (u16*)(ws + 24 * MB);
  u16* WkT = (u16*)(ws + 26 * MB);
  u16* WvT = (u16*)(ws + 28 * MB);
  u16* WoT = (u16*)(ws + 30 * MB);
  u16* Qb  = (u16*)(ws + 32 * MB);
  u16* Kb  = (u16*)(ws + 40 * MB);
  u16* Vb  = (u16*)(ws + 48 * MB);
  u16* AO  = (u16*)(ws + 56 * MB);
  float* lwbuf = (float*)(ws + 64 * MB);
  u16* VtT = (u16*)(ws + 16 * MB);   // V transposed (b,h,dk,s), overwrites Xv after use

  kprep_conv<<<dim3(4096, 3), 256, 0, stream>>>(query, key_, value, Xq, Xk, Xv);
  kprep_wt<<<dim3(32, 32, 4), 256, 0, stream>>>(wq, wk, wv, wo, WqT, WkT, WvT, WoT);
  klw<<<16, 256, 0, stream>>>(wts, lwbuf);
  kgemm_qkv<<<dim3(8, 32, 3), 256, 0, stream>>>(Xq, Xk, Xv, WqT, WkT, WvT, bq, bk, bv, Qb, Kb, Vb);
  ktrans_v<<<dim3(32, 32), 256, 0, stream>>>(Vb, VtT);
  kattn<<<512, 256, 0, stream>>>(Qb, Kb, VtT, lwbuf, AO);
  kgemm_o<<<dim3(8, 32), 256, 0, stream>>>(AO, WoT, bo, out);
}